// Round 1
// baseline (179.770 us; speedup 1.0000x reference)
//
#include <hip/hip_runtime.h>

#define SAMPLES 128
#define HID 256
#define NEARV 0.1f
#define FARV 4.0f
#define DZ ((FARV - NEARV) / (SAMPLES - 1))
#define EPSV 1e-6f

typedef __attribute__((ext_vector_type(8))) short v8s;   // 8 x bf16
typedef __attribute__((ext_vector_type(4))) float v4f;   // 4 x fp32

__device__ __forceinline__ unsigned short f2b(float f) {
  union { float f; unsigned u; } v; v.f = f;
  return (unsigned short)((v.u + 0x7fffu + ((v.u >> 16) & 1u)) >> 16);  // RNE
}

// Swizzled LDS address for the 128x256 bf16 h-buffer. Chunk = 8 bf16 = 16B.
// chunk column XOR'd with (m & 15) -> A-fragment reads (16 consecutive m,
// fixed k-chunk) spread across banks; <=2-way aliasing (free, m136).
__device__ __forceinline__ int haddr(int m, int k) {
  return m * 256 + ((((k >> 3) ^ (m & 15)) << 3) | (k & 7));
}

// Pack W2 (fp32 [K=256][N=256], row-major k) into bf16 B-fragment-linear
// layout: chunk index ((gnt*8 + kt)*4 + quad)*16 + lane16 holds
// B[k = kt*32+quad*8 .. +8)][n = gnt*16+lane16]  (k-contiguous 8).
__global__ void pack_w2(const float* __restrict__ W2, unsigned short* __restrict__ out) {
  int t = blockIdx.x * 256 + threadIdx.x;   // 0..8191
  int l16 = t & 15;
  int q   = (t >> 4) & 3;
  int kt  = (t >> 6) & 7;
  int gnt = t >> 9;
  int n  = gnt * 16 + l16;
  int k0 = kt * 32 + q * 8;
#pragma unroll
  for (int j = 0; j < 8; ++j) out[t * 8 + j] = f2b(W2[(k0 + j) * 256 + n]);
}

// Pack head weights [Wsig | Wrgb(:256) | zeros] (K=256, N=16) the same way.
__global__ void pack_head(const float* __restrict__ Wsig, const float* __restrict__ Wrgb,
                          unsigned short* __restrict__ out) {
  int t = blockIdx.x * 256 + threadIdx.x;   // 0..511
  if (t >= 512) return;
  int n = t & 15, q = (t >> 4) & 3, kt = t >> 6;
  int k0 = kt * 32 + q * 8;
#pragma unroll
  for (int j = 0; j < 8; ++j) {
    int k = k0 + j;
    float v = 0.f;
    if (n == 0)      v = Wsig[k];
    else if (n < 4)  v = Wrgb[k * 3 + (n - 1)];
    out[t * 8 + j] = f2b(v);
  }
}

// One block per ray: 512 threads = 8 waves. M=128 samples.
__global__ __launch_bounds__(512, 4) void render(
    const float* __restrict__ cam, const float* __restrict__ rayv,
    const float* __restrict__ W1, const float* __restrict__ b1,
    const float* __restrict__ b2, const float* __restrict__ bsig,
    const float* __restrict__ Wrgb, const float* __restrict__ brgb,
    const unsigned short* __restrict__ W2p, const unsigned short* __restrict__ Hdp,
    float* __restrict__ out) {
  __shared__ __align__(16) unsigned short smem[128 * 256];  // 64 KB, multi-purpose

  const int tid = threadIdx.x;
  const int ray = blockIdx.x;

  // Per-ray data (broadcast loads, L1-hot)
  float rvx = rayv[ray * 3 + 0], rvy = rayv[ray * 3 + 1], rvz = rayv[ray * 3 + 2];
  float rn  = 1.0f / sqrtf(rvx * rvx + rvy * rvy + rvz * rvz);
  float rdx = rvx * rn, rdy = rvy * rn, rdz = rvz * rn;
  float cx = cam[ray * 3 + 0], cy = cam[ray * 3 + 1], cz = cam[ray * 3 + 2];

  // ---- Layer 1: h1[m][n] = relu(pts[m] . W1[:,n] + b1[n]) -> LDS bf16
  {
    int n4 = (tid & 63) * 4;     // each thread owns 4 consecutive n, all m via loop
    int m0 = tid >> 6;           // 0..7
    float4 wa = *(const float4*)(W1 + n4);
    float4 wb = *(const float4*)(W1 + 256 + n4);
    float4 wc = *(const float4*)(W1 + 512 + n4);
    float4 bb = *(const float4*)(b1 + n4);
#pragma unroll
    for (int r = 0; r < 16; ++r) {
      int m = m0 + r * 8;
      float z = NEARV + DZ * (float)m;
      float px = cx + rdx * z, py = cy + rdy * z, pz = cz + rdz * z;
      float v0 = fmaxf(bb.x + px * wa.x + py * wb.x + pz * wc.x, 0.f);
      float v1 = fmaxf(bb.y + px * wa.y + py * wb.y + pz * wc.y, 0.f);
      float v2 = fmaxf(bb.z + px * wa.z + py * wb.z + pz * wc.z, 0.f);
      float v3 = fmaxf(bb.w + px * wa.w + py * wb.w + pz * wc.w, 0.f);
      ushort4 pk; pk.x = f2b(v0); pk.y = f2b(v1); pk.z = f2b(v2); pk.w = f2b(v3);
      *(ushort4*)(smem + haddr(m, n4)) = pk;   // ds_write_b64
    }
  }
  __syncthreads();

  const int lane = tid & 63;
  const int wv   = tid >> 6;        // 0..7
  const int q    = lane >> 4;       // quad
  const int l16  = lane & 15;
  const int mw   = (wv >> 2) * 64;  // 2-way M split
  const int nw   = (wv & 3) * 64;   // 4-way N split

  // ---- Layer 2 GEMM: h2 = relu(h1 @ W2 + b2), M=128 N=256 K=256
  v4f acc[4][4];
#pragma unroll
  for (int i = 0; i < 4; ++i)
#pragma unroll
    for (int j = 0; j < 4; ++j) acc[i][j] = (v4f)(0.f);

  const v8s* Bp = (const v8s*)W2p;
#pragma unroll
  for (int kt = 0; kt < 8; ++kt) {
    int k0 = kt * 32 + q * 8;
    v8s af[4], bf[4];
#pragma unroll
    for (int mt = 0; mt < 4; ++mt)
      af[mt] = *(const v8s*)(smem + haddr(mw + mt * 16 + l16, k0));  // ds_read_b128
#pragma unroll
    for (int nt = 0; nt < 4; ++nt) {
      int gnt = (nw >> 4) + nt;
      bf[nt] = Bp[((gnt * 8 + kt) * 4 + q) * 16 + l16];              // coalesced 1KB/wave
    }
#pragma unroll
    for (int mt = 0; mt < 4; ++mt)
#pragma unroll
      for (int nt = 0; nt < 4; ++nt)
        acc[mt][nt] = __builtin_amdgcn_mfma_f32_16x16x32_bf16(af[mt], bf[nt], acc[mt][nt], 0, 0, 0);
  }
  __syncthreads();   // all h1 reads done; reuse smem for h2

  // ---- epilogue: h2 -> LDS (C layout: row m = quad*4+reg, col n = lane16)
  {
    float b2v[4];
#pragma unroll
    for (int nt = 0; nt < 4; ++nt) b2v[nt] = b2[nw + nt * 16 + l16];
#pragma unroll
    for (int mt = 0; mt < 4; ++mt)
#pragma unroll
      for (int nt = 0; nt < 4; ++nt)
#pragma unroll
        for (int r = 0; r < 4; ++r) {
          int m = mw + mt * 16 + q * 4 + r;
          int n = nw + nt * 16 + l16;
          smem[haddr(m, n)] = f2b(fmaxf(acc[mt][nt][r] + b2v[nt], 0.f));
        }
  }
  __syncthreads();

  // ---- heads via one MFMA chain per wave: [sigma|r|g|b|pad] = h2 @ Hd
  v4f hacc = (v4f)(0.f);
  const v8s* Hp = (const v8s*)Hdp;
#pragma unroll
  for (int kt = 0; kt < 8; ++kt) {
    v8s a = *(const v8s*)(smem + haddr(wv * 16 + l16, kt * 32 + q * 8));
    v8s b = Hp[(kt * 4 + q) * 16 + l16];
    hacc = __builtin_amdgcn_mfma_f32_16x16x32_bf16(a, b, hacc, 0, 0, 0);
  }
  __syncthreads();   // h2 reads done; smem now reused as fp32 scratch

  // fb[0..511]: per-sample {alpha, r, g, b}; fb[512..639]: scan; fb[640..1151]: reduce
  float* fb = (float*)smem;
  if (l16 < 4) {
#pragma unroll
    for (int r = 0; r < 4; ++r) {
      int m = wv * 16 + q * 4 + r;
      float v = hacc[r];
      if (l16 == 0) {
        float sg = fmaxf(v + bsig[0], 0.f);
        float a  = (m == SAMPLES - 1) ? 1.0f : (1.0f - __expf(-sg * DZ));
        fb[m * 4 + 0] = a;
      } else {
        int c = l16 - 1;
        // view-dir contribution: dirs = -rd, rows 256..258 of Wrgb
        float dd = -(rdx * Wrgb[768 + c] + rdy * Wrgb[771 + c] + rdz * Wrgb[774 + c]);
        v += brgb[c] + dd;
        fb[m * 4 + l16] = 1.0f / (1.0f + __expf(-v));
      }
    }
  }
  __syncthreads();

  // ---- volume rendering: exclusive cumprod of (1 - alpha + eps), weights, sum
  float am = 0.f, r0 = 0.f, g0 = 0.f, b0 = 0.f;
  if (tid < SAMPLES) {
    am = fb[tid * 4 + 0];
    r0 = fb[tid * 4 + 1];
    g0 = fb[tid * 4 + 2];
    b0 = fb[tid * 4 + 3];
    fb[512 + tid] = 1.0f - am + EPSV;
  }
  __syncthreads();
  for (int off = 1; off < SAMPLES; off <<= 1) {   // Hillis-Steele inclusive cumprod
    float v = 1.0f;
    if (tid < SAMPLES && tid >= off) v = fb[512 + tid - off];
    __syncthreads();
    if (tid < SAMPLES) fb[512 + tid] *= v;
    __syncthreads();
  }
  if (tid < SAMPLES) {
    float trans = (tid == 0) ? 1.0f : fb[512 + tid - 1];
    float wgt = am * trans;
    fb[640 + tid * 4 + 0] = wgt * r0;
    fb[640 + tid * 4 + 1] = wgt * g0;
    fb[640 + tid * 4 + 2] = wgt * b0;
  }
  __syncthreads();
  for (int off = 64; off >= 1; off >>= 1) {
    if (tid < off) {
      fb[640 + tid * 4 + 0] += fb[640 + (tid + off) * 4 + 0];
      fb[640 + tid * 4 + 1] += fb[640 + (tid + off) * 4 + 1];
      fb[640 + tid * 4 + 2] += fb[640 + (tid + off) * 4 + 2];
    }
    __syncthreads();
  }
  if (tid == 0) {
    out[ray * 3 + 0] = fb[640 + 0];
    out[ray * 3 + 1] = fb[640 + 1];
    out[ray * 3 + 2] = fb[640 + 2];
  }
}

extern "C" void kernel_launch(void* const* d_in, const int* in_sizes, int n_in,
                              void* d_out, int out_size, void* d_ws, size_t ws_size,
                              hipStream_t stream) {
  const float* cam  = (const float*)d_in[0];
  const float* rayv = (const float*)d_in[1];
  const float* W1   = (const float*)d_in[2];
  const float* b1   = (const float*)d_in[3];
  const float* W2   = (const float*)d_in[4];
  const float* b2   = (const float*)d_in[5];
  const float* Wsig = (const float*)d_in[6];
  const float* bsig = (const float*)d_in[7];
  const float* Wrgb = (const float*)d_in[8];
  const float* brgb = (const float*)d_in[9];
  float* out = (float*)d_out;

  unsigned short* W2p = (unsigned short*)d_ws;     // 256*256 bf16 = 128 KB
  unsigned short* Hdp = W2p + 256 * 256;           // 256*16 bf16 = 8 KB

  int R = in_sizes[0] / 3;                         // B*N rays (4096)

  pack_w2<<<32, 256, 0, stream>>>(W2, W2p);
  pack_head<<<2, 256, 0, stream>>>(Wsig, Wrgb, Hdp);
  render<<<R, 512, 0, stream>>>(cam, rayv, W1, b1, b2, bsig, Wrgb, brgb, W2p, Hdp, out);
}